// Round 13
// baseline (581.632 us; speedup 1.0000x reference)
//
#include <hip/hip_runtime.h>

typedef __attribute__((ext_vector_type(8))) short short8;
typedef __attribute__((ext_vector_type(4))) short short4v;
typedef __attribute__((ext_vector_type(4))) float f32x4;
typedef __attribute__((ext_vector_type(8))) unsigned short u16x8;

#define B_ 4
#define S_ 2048
#define EMB_ 512
#define HID_ 512
#define VOCAB_ 32000
#define ROWS (B_ * S_)          // 8192
#define NCHUNK 32
#define CHUNK 64                // NCHUNK*CHUNK == S_

// persistent final GEMM geometry (R8 structure)
#define FK_ 512
#define NBN_F 125
#define OT_PER_BLK 16
#define NBLK_F (NBN_F * 2)
#define NT_TOT (OT_PER_BLK * 8)
#define BIAS_OFF 131072
#define SMEM_TOT (BIAS_OFF + 1024)   // 132096

__device__ __forceinline__ unsigned short f2bf(float f) {
    unsigned int u = __float_as_uint(f);
    u += 0x7fffu + ((u >> 16) & 1u);
    return (unsigned short)(u >> 16);
}

__device__ __forceinline__ void gl_lds16(const void* g, void* l) {
    __builtin_amdgcn_global_load_lds(
        (const __attribute__((address_space(1))) unsigned int*)(uintptr_t)(g),
        (__attribute__((address_space(3))) unsigned int*)(unsigned int)(uintptr_t)(l),
        16, 0, 0);
}

// ---------------- standalone transpose+convert (fallback path only) ----------------
__global__ __launch_bounds__(256) void transpose_convert_k(
    const float* __restrict__ src, unsigned short* __restrict__ dst, int K, int N) {
    __shared__ float t[32][33];
    int kt = blockIdx.y * 32, nt = blockIdx.x * 32;
    int tx = threadIdx.x & 31, ty = threadIdx.x >> 5;
#pragma unroll
    for (int i = 0; i < 4; i++)
        t[ty + i * 8][tx] = src[(size_t)(kt + ty + i * 8) * N + nt + tx];
    __syncthreads();
#pragma unroll
    for (int i = 0; i < 4; i++)
        dst[(size_t)(nt + ty + i * 8) * K + kt + tx] = f2bf(t[tx][ty + i * 8]);
}

// ---------------- fused prep: embed+LN0 | 64x64 transpose of W0 | W1 | fc_w (R12) ----------------
__global__ __launch_bounds__(256) void prep_k(
    const int* __restrict__ ids, const float* __restrict__ emb,
    const float* __restrict__ gam, const float* __restrict__ bet,
    float* __restrict__ xres, unsigned short* __restrict__ xw,
    const float* __restrict__ W0, unsigned short* __restrict__ wt0,
    const float* __restrict__ W1, unsigned short* __restrict__ wt1,
    const float* __restrict__ fcw, unsigned short* __restrict__ fcwt) {
    __shared__ float t[64][69];
    int vb = blockIdx.x;
    int tid = threadIdx.x;
    if (vb < 2048) {
        int row = vb * 4 + (tid >> 6);
        int lane = tid & 63;
        const float4* src = (const float4*)(emb + (size_t)ids[row] * EMB_);
        float v[8];
        *(float4*)(v) = src[lane * 2];
        *(float4*)(v + 4) = src[lane * 2 + 1];
        float s = 0.f, s2 = 0.f;
#pragma unroll
        for (int j = 0; j < 8; j++) { s += v[j]; s2 += v[j] * v[j]; }
#pragma unroll
        for (int off = 1; off < 64; off <<= 1) {
            s += __shfl_xor(s, off);
            s2 += __shfl_xor(s2, off);
        }
        float mu = s * (1.f / EMB_);
        float var = fmaxf(s2 * (1.f / EMB_) - mu * mu, 0.f);
        float rstd = rsqrtf(var + 1e-5f);
        float4* xr = (float4*)(xres + (size_t)row * EMB_);
        xr[lane * 2] = *(float4*)(v);
        xr[lane * 2 + 1] = *(float4*)(v + 4);
        u16x8 o;
#pragma unroll
        for (int j = 0; j < 8; j++) {
            int c = lane * 8 + j;
            o[j] = f2bf((v[j] - mu) * rstd * gam[c] + bet[c]);
        }
        *(u16x8*)(xw + (size_t)row * EMB_ + lane * 8) = o;
        return;
    }
    vb -= 2048;
    const float* src;
    unsigned short* dst;
    int N;
    if (vb < 128)        { src = W0;  dst = wt0;  N = 1024; }
    else if (vb < 256)   { vb -= 128; src = W1;  dst = wt1;  N = 1024; }
    else                 { vb -= 256; src = fcw; dst = fcwt; N = VOCAB_; }
    int ntiles = N >> 6;
    int ktile = vb / ntiles, ntile = vb - ktile * ntiles;
    int kt = ktile << 6, nt = ntile << 6;
    int tx = tid & 15, ty = tid >> 4;
#pragma unroll
    for (int i = 0; i < 4; i++) {
        int r = ty + 16 * i;
        float4 v = *(const float4*)(src + (size_t)(kt + r) * N + nt + tx * 4);
        t[r][tx * 4 + 0] = v.x;
        t[r][tx * 4 + 1] = v.y;
        t[r][tx * 4 + 2] = v.z;
        t[r][tx * 4 + 3] = v.w;
    }
    __syncthreads();
#pragma unroll
    for (int i = 0; i < 4; i++) {
        int d = ty + 16 * i;
        short4v o;
#pragma unroll
        for (int j = 0; j < 4; j++)
            o[j] = (short)f2bf(t[tx * 4 + j][d]);
        *(short4v*)(dst + (size_t)(nt + d) * 512 + kt + tx * 4) = o;
    }
}

// ---------------- LayerNorm of xsrc -> bf16 xw ----------------
__global__ __launch_bounds__(256) void ln_k(
    const float* __restrict__ xsrc,
    const float* __restrict__ gam, const float* __restrict__ bet,
    unsigned short* __restrict__ xw, float eps) {
    int row = blockIdx.x * 4 + (threadIdx.x >> 6);
    int lane = threadIdx.x & 63;
    const float4* src = (const float4*)(xsrc + (size_t)row * HID_);
    float v[8];
    *(float4*)(v) = src[lane * 2];
    *(float4*)(v + 4) = src[lane * 2 + 1];
    float s = 0.f, s2 = 0.f;
#pragma unroll
    for (int j = 0; j < 8; j++) { s += v[j]; s2 += v[j] * v[j]; }
#pragma unroll
    for (int off = 1; off < 64; off <<= 1) {
        s += __shfl_xor(s, off);
        s2 += __shfl_xor(s2, off);
    }
    float mu = s * (1.f / HID_);
    float var = fmaxf(s2 * (1.f / HID_) - mu * mu, 0.f);
    float rstd = rsqrtf(var + eps);
    u16x8 o;
#pragma unroll
    for (int j = 0; j < 8; j++) {
        int c = lane * 8 + j;
        o[j] = f2bf((v[j] - mu) * rstd * gam[c] + bet[c]);
    }
    *(u16x8*)(xw + (size_t)row * HID_ + lane * 8) = o;
}

// ---------------- layer GEMM: 128x128 tile, BK=64, 4 waves; LDS-transpose epilogue (R4) ----------------
__global__ __launch_bounds__(256) void gemm_bf16_k(
    const unsigned short* __restrict__ A, const unsigned short* __restrict__ Bt,
    float* __restrict__ C, int M, int N, int K) {
    __shared__ unsigned short lA[128 * 64];
    __shared__ unsigned short lB[128 * 64];
    __shared__ float eT[4][16 * 68];
    int tid = threadIdx.x;
    int w = tid >> 6, l = tid & 63;
    int m0 = blockIdx.y * 128, n0 = blockIdx.x * 128;
    int wm = w >> 1, wn = w & 1;
    f32x4 acc[4][4] = {};

    int rIn = l >> 3;
    int cOff = (l & 7) * 8;

    for (int k0 = 0; k0 < K; k0 += 64) {
#pragma unroll
        for (int i = 0; i < 4; i++) {
            int c = w * 4 + i;
            gl_lds16(A + (size_t)(m0 + c * 8 + rIn) * K + k0 + cOff, &lA[c * 512]);
            gl_lds16(Bt + (size_t)(n0 + c * 8 + rIn) * K + k0 + cOff, &lB[c * 512]);
        }
        asm volatile("s_waitcnt vmcnt(0)" ::: "memory");
        __syncthreads();

        const unsigned short* pa = lA + ((size_t)(wm * 64 + (l & 15)) * 64) + ((l >> 4) * 8);
        const unsigned short* pb = lB + ((size_t)(wn * 64 + (l & 15)) * 64) + ((l >> 4) * 8);
#pragma unroll
        for (int kk = 0; kk < 2; kk++) {
            short8 af[4], bfr[4];
#pragma unroll
            for (int m = 0; m < 4; m++) af[m] = *(const short8*)(pa + m * 16 * 64 + kk * 32);
#pragma unroll
            for (int n = 0; n < 4; n++) bfr[n] = *(const short8*)(pb + n * 16 * 64 + kk * 32);
#pragma unroll
            for (int m = 0; m < 4; m++)
#pragma unroll
                for (int n = 0; n < 4; n++)
                    acc[m][n] = __builtin_amdgcn_mfma_f32_16x16x32_bf16(af[m], bfr[n], acc[m][n], 0, 0, 0);
        }
        __syncthreads();
    }

    float* ep = eT[w];
    int rl = l >> 4, slot = l & 15;
    int rbase = m0 + wm * 64, cbase = n0 + wn * 64;
#pragma unroll
    for (int mf = 0; mf < 4; ++mf) {
#pragma unroll
        for (int nf = 0; nf < 4; ++nf)
#pragma unroll
            for (int j = 0; j < 4; ++j)
                ep[(rl * 4 + j) * 68 + nf * 16 + slot] = acc[mf][nf][j];
        asm volatile("s_waitcnt lgkmcnt(0)" ::: "memory");
#pragma unroll
        for (int p = 0; p < 4; ++p) {
            int r = p * 4 + rl;
            f32x4 vv = *(const f32x4*)(ep + r * 68 + slot * 4);
            *(f32x4*)(C + (size_t)(rbase + mf * 16 + r) * N + cbase + slot * 4) = vv;
        }
        asm volatile("s_waitcnt lgkmcnt(0)" ::: "memory");
    }
}

// ---------------- persistent final GEMM: R8 pipeline + swapped-operand register-direct NT epilogue ----
__device__ __forceinline__ void stageP(
    const unsigned short* __restrict__ A, const unsigned short* __restrict__ Bt,
    int bmbase, int bn, int H, char* smem, int r0, int c0, unsigned wq) {
    if (H >= 4 * NT_TOT) return;
    int T = H >> 2, j = H & 3;
    int ti = T >> 3, kt = T & 7;
    const unsigned short* src = (j < 2) ? A : Bt;
    int row0 = ((j < 2) ? ((bmbase + ti) << 8) : (bn << 8)) + ((j & 1) << 7);
    unsigned tb = ((unsigned)(T & 1) << 16) | ((unsigned)(j >> 1) << 15) | ((unsigned)(j & 1) << 14);
    const unsigned short* g0 = src + (size_t)(row0 + r0) * FK_ + ((kt << 6) + c0);
    gl_lds16(g0, (unsigned short*)(smem + tb + wq));
    gl_lds16(g0 + (size_t)64 * FK_, (unsigned short*)(smem + tb + 8192 + wq));
}

#define MIDBAR() __builtin_amdgcn_s_barrier()
#define ENDBAR() do { asm volatile("s_waitcnt lgkmcnt(0)" ::: "memory"); \
                      asm volatile("s_barrier" ::: "memory"); } while (0)

// swapped operands: D = mfma(B, A) -> lane holds m = l&15 fixed, n = (l>>4)*4+j consecutive
#define PHASE_MFMA(AF, BF, MO, NO)                                                  \
    do {                                                                            \
        __builtin_amdgcn_s_setprio(1);                                             \
        _Pragma("unroll") for (int mf = 0; mf < 4; ++mf)                            \
        _Pragma("unroll") for (int nf = 0; nf < 2; ++nf)                            \
        _Pragma("unroll") for (int ks = 0; ks < 2; ++ks)                            \
            acc[(MO) + mf][(NO) + nf] = __builtin_amdgcn_mfma_f32_16x16x32_bf16(    \
                BF[nf][ks], AF[mf][ks], acc[(MO) + mf][(NO) + nf], 0, 0, 0);        \
        __builtin_amdgcn_s_setprio(0);                                             \
    } while (0)

__global__ __launch_bounds__(512, 2) void gemmP_k(
    const unsigned short* __restrict__ A, const unsigned short* __restrict__ Bt,
    const float* __restrict__ bias, float* __restrict__ C) {
    extern __shared__ char smem[];
    int tid = threadIdx.x;
    int w = tid >> 6, l = tid & 63;
    int wm = w >> 2, wn = w & 3;

    int bn = blockIdx.x % NBN_F;
    int bmbase = (blockIdx.x / NBN_F) * OT_PER_BLK;

    int r0 = ((w >> 1) << 4) + (l >> 2);
    int c0 = ((w & 1) << 5) + (((l & 3) << 3) ^ ((l & 32) ? 16 : 0));
    unsigned wq = (unsigned)(w << 10);

    unsigned rowpart = (unsigned)(((l & 15) << 6) + (((((l >> 4) << 3)) ^ ((l & 8) ? 16 : 0)) << 1));
    unsigned aoff = ((unsigned)wm << 14) + rowpart;
    unsigned boff = 32768u + ((unsigned)wn << 13) + rowpart;

    f32x4 acc[8][4] = {};

    if (tid < 64) {
        f32x4 bv = *(const f32x4*)(bias + (bn << 8) + (tid << 2));
        *(f32x4*)(smem + BIAS_OFF + (tid << 4)) = bv;
    }
    asm volatile("s_waitcnt vmcnt(0) lgkmcnt(0)" ::: "memory");
    asm volatile("" ::: "memory");

    stageP(A, Bt, bmbase, bn, 0, smem, r0, c0, wq); asm volatile("" ::: "memory");
    stageP(A, Bt, bmbase, bn, 1, smem, r0, c0, wq); asm volatile("" ::: "memory");
    stageP(A, Bt, bmbase, bn, 2, smem, r0, c0, wq); asm volatile("" ::: "memory");
    stageP(A, Bt, bmbase, bn, 3, smem, r0, c0, wq); asm volatile("" ::: "memory");
    stageP(A, Bt, bmbase, bn, 4, smem, r0, c0, wq); asm volatile("" ::: "memory");
    stageP(A, Bt, bmbase, bn, 5, smem, r0, c0, wq);
    asm volatile("s_waitcnt vmcnt(4)" ::: "memory");
    asm volatile("s_barrier" ::: "memory");

    for (int T = 0; T < NT_TOT; ++T) {
        const char* pA = smem + (((unsigned)(T & 1)) << 16) + aoff;
        const char* pB = smem + (((unsigned)(T & 1)) << 16) + boff;
        short8 A0[4][2], A1[4][2], B0[2][2], B1[2][2];

#pragma unroll
        for (int mf = 0; mf < 4; ++mf)
#pragma unroll
            for (int ks = 0; ks < 2; ++ks)
                A0[mf][ks] = *(const short8*)(pA + mf * 2048 + ks * 1024);
#pragma unroll
        for (int nf = 0; nf < 2; ++nf)
#pragma unroll
            for (int ks = 0; ks < 2; ++ks)
                B0[nf][ks] = *(const short8*)(pB + nf * 2048 + ks * 1024);
        stageP(A, Bt, bmbase, bn, 4 * T + 6, smem, r0, c0, wq);
        MIDBAR();
        PHASE_MFMA(A0, B0, 0, 0);
        ENDBAR();

#pragma unroll
        for (int mf = 0; mf < 4; ++mf)
#pragma unroll
            for (int ks = 0; ks < 2; ++ks)
                A1[mf][ks] = *(const short8*)(pA + (4 + mf) * 2048 + ks * 1024);
#pragma unroll
        for (int nf = 0; nf < 2; ++nf)
#pragma unroll
            for (int ks = 0; ks < 2; ++ks)
                B1[nf][ks] = *(const short8*)(pB + (2 + nf) * 2048 + ks * 1024);
        stageP(A, Bt, bmbase, bn, 4 * T + 7, smem, r0, c0, wq);
        MIDBAR();
        PHASE_MFMA(A1, B0, 4, 0);
        ENDBAR();

        stageP(A, Bt, bmbase, bn, 4 * T + 8, smem, r0, c0, wq);
        MIDBAR();
        PHASE_MFMA(A1, B1, 4, 2);
        ENDBAR();

        stageP(A, Bt, bmbase, bn, 4 * T + 9, smem, r0, c0, wq);
        if (T < NT_TOT - 2)       { asm volatile("s_waitcnt vmcnt(4)" ::: "memory"); }
        else if (T == NT_TOT - 2) { asm volatile("s_waitcnt vmcnt(0)" ::: "memory"); }
        MIDBAR();
        PHASE_MFMA(A0, B1, 0, 2);
        ENDBAR();

        // register-direct epilogue (R5-verified mapping) + NT stores (R7) — zero LDS ops
        if ((T & 7) == 7) {
            int bm = bmbase + (T >> 3);
            const float* bls = (const float*)(smem + BIAS_OFF);
            int rbase = (bm << 8) + (wm << 7) + (l & 15);
            int cloc = (wn << 6) + ((l >> 4) << 2);
#pragma unroll
            for (int nf = 0; nf < 4; ++nf) {
                f32x4 bv = *(const f32x4*)(bls + cloc + nf * 16);
#pragma unroll
                for (int mf = 0; mf < 8; ++mf) {
                    f32x4 vv = acc[mf][nf] + bv;
                    __builtin_nontemporal_store(vv,
                        (f32x4*)(C + (size_t)(rbase + (mf << 4)) * VOCAB_ +
                                 (bn << 8) + cloc + nf * 16));
                    acc[mf][nf] = f32x4{0.f, 0.f, 0.f, 0.f};
                }
            }
        }
    }
}

// ---------------- minGRU scan (R8: CHUNK=64) ----------------
__device__ __forceinline__ void gate_terms(float k, float hp, float& a, float& b) {
    float z = 1.f / (1.f + __expf(-k));
    a = 1.f - z;
    float g = (hp >= 0.f) ? (hp + 0.5f) : (1.f / (1.f + __expf(-hp)));
    b = z * g;
}

__global__ __launch_bounds__(256) void scan1_k(
    const float* __restrict__ proj, float* __restrict__ Ach, float* __restrict__ Bch) {
    int t = blockIdx.x * 256 + threadIdx.x;
    int h = t & (HID_ - 1);
    int bc = t >> 9;
    int b = bc >> 5, c = bc & (NCHUNK - 1);
    const float* p = proj + ((size_t)(b * S_ + c * CHUNK)) * (2 * HID_) + h;
    float A = 1.f, H = 0.f;
#pragma unroll 4
    for (int s = 0; s < CHUNK; s++) {
        float k = p[(size_t)s * (2 * HID_)];
        float hp = p[(size_t)s * (2 * HID_) + HID_];
        float a, bb;
        gate_terms(k, hp, a, bb);
        H = a * H + bb;
        A *= a;
    }
    Ach[t] = A;
    Bch[t] = H;
}

__global__ __launch_bounds__(256) void scan23_k(
    const float* __restrict__ proj, const float* __restrict__ Ach,
    const float* __restrict__ Bch, float* __restrict__ xres) {
    int t = blockIdx.x * 256 + threadIdx.x;
    int h = t & (HID_ - 1);
    int bc = t >> 9;
    int b = bc >> 5, c = bc & (NCHUNK - 1);
    float H = 0.f;
    for (int cp = 0; cp < c; cp++) {
        int idx = (b * NCHUNK + cp) * HID_ + h;
        H = Ach[idx] * H + Bch[idx];
    }
    const float* p = proj + ((size_t)(b * S_ + c * CHUNK)) * (2 * HID_) + h;
    float* x = xres + ((size_t)(b * S_ + c * CHUNK)) * HID_ + h;
#pragma unroll 4
    for (int s = 0; s < CHUNK; s++) {
        float k = p[(size_t)s * (2 * HID_)];
        float hp = p[(size_t)s * (2 * HID_) + HID_];
        float a, bb;
        gate_terms(k, hp, a, bb);
        H = a * H + bb;
        x[(size_t)s * HID_] += H;
    }
}

// ---------------- launch ----------------
extern "C" void kernel_launch(void* const* d_in, const int* in_sizes, int n_in,
                              void* d_out, int out_size, void* d_ws, size_t ws_size,
                              hipStream_t stream) {
    const int* ids = (const int*)d_in[0];
    const float* emb = (const float*)d_in[1];
    const float* W0 = (const float*)d_in[2];
    const float* W1 = (const float*)d_in[3];
    const float* ln0_g = (const float*)d_in[4];
    const float* ln0_b = (const float*)d_in[5];
    const float* ln1_g = (const float*)d_in[6];
    const float* ln1_b = (const float*)d_in[7];
    const float* lnf_g = (const float*)d_in[8];
    const float* lnf_b = (const float*)d_in[9];
    const float* fc_w = (const float*)d_in[10];
    const float* fc_b = (const float*)d_in[11];
    float* out = (float*)d_out;

    (void)hipFuncSetAttribute((const void*)gemmP_k,
                              hipFuncAttributeMaxDynamicSharedMemorySize, SMEM_TOT);

    char* ws = (char*)d_ws;
    const size_t OFF_XW   = 0;
    const size_t OFF_PROJ = 8388608;
    const size_t OFF_XRES = OFF_PROJ + 33554432;
    const size_t OFF_WT0  = OFF_XRES + 16777216;
    const size_t OFF_WT1  = OFF_WT0 + 1048576;
    const size_t OFF_SA   = OFF_WT1 + 1048576;
    const size_t OFF_SB   = OFF_SA + 262144;
    const size_t OFF_FCWT = OFF_SB + 262144;
    const size_t NEED_BIG = OFF_FCWT + 32768000;

    unsigned short* xw  = (unsigned short*)(ws + OFF_XW);
    float* proj         = (float*)(ws + OFF_PROJ);
    float* xres         = (float*)(ws + OFF_XRES);
    unsigned short* wt0 = (unsigned short*)(ws + OFF_WT0);
    unsigned short* wt1 = (unsigned short*)(ws + OFF_WT1);
    float* sA = (float*)(ws + OFF_SA);
    float* sB = (float*)(ws + OFF_SB);

    bool big = ws_size >= NEED_BIG;
    unsigned short* fcwt = big ? (unsigned short*)(ws + OFF_FCWT)
                               : (unsigned short*)(ws + OFF_PROJ);

    if (big) {
        prep_k<<<2048 + 128 + 128 + 4000, 256, 0, stream>>>(
            ids, emb, ln0_g, ln0_b, xres, xw, W0, wt0, W1, wt1, fc_w, fcwt);
    } else {
        prep_k<<<2048 + 128 + 128, 256, 0, stream>>>(
            ids, emb, ln0_g, ln0_b, xres, xw, W0, wt0, W1, wt1, fc_w, wt0);
    }

    // layer 0
    gemm_bf16_k<<<dim3(1024 / 128, ROWS / 128), 256, 0, stream>>>(xw, wt0, proj, ROWS, 1024, 512);
    scan1_k<<<65536 / 256, 256, 0, stream>>>(proj, sA, sB);
    scan23_k<<<65536 / 256, 256, 0, stream>>>(proj, sA, sB, xres);

    // layer 1
    ln_k<<<ROWS / 4, 256, 0, stream>>>(xres, ln1_g, ln1_b, xw, 1e-5f);
    gemm_bf16_k<<<dim3(1024 / 128, ROWS / 128), 256, 0, stream>>>(xw, wt1, proj, ROWS, 1024, 512);
    scan1_k<<<65536 / 256, 256, 0, stream>>>(proj, sA, sB);
    scan23_k<<<65536 / 256, 256, 0, stream>>>(proj, sA, sB, xres);

    // final LN (eps=0.0) + logits
    ln_k<<<ROWS / 4, 256, 0, stream>>>(xres, lnf_g, lnf_b, xw, 0.0f);
    if (!big) {
        transpose_convert_k<<<dim3(VOCAB_ / 32, 512 / 32), 256, 0, stream>>>(fc_w, fcwt, 512, VOCAB_);
    }
    gemmP_k<<<NBLK_F, 512, SMEM_TOT, stream>>>(xw, fcwt, fc_b, out);
}

// Round 14
// 549.789 us; speedup vs baseline: 1.0579x; 1.0579x over previous
//
#include <hip/hip_runtime.h>

typedef __attribute__((ext_vector_type(8))) short short8;
typedef __attribute__((ext_vector_type(4))) short short4v;
typedef __attribute__((ext_vector_type(4))) float f32x4;
typedef __attribute__((ext_vector_type(8))) unsigned short u16x8;

#define B_ 4
#define S_ 2048
#define EMB_ 512
#define HID_ 512
#define VOCAB_ 32000
#define ROWS (B_ * S_)          // 8192
#define NCHUNK 32
#define CHUNK 64                // NCHUNK*CHUNK == S_

// persistent final GEMM geometry (R8/R12 structure)
#define FK_ 512
#define NBN_F 125
#define OT_PER_BLK 16
#define NBLK_F (NBN_F * 2)
#define NT_TOT (OT_PER_BLK * 8)
#define EP_OFF 131072
#define BIAS_OFF (EP_OFF + 20480)
#define SMEM_TOT (BIAS_OFF + 1024)

__device__ __forceinline__ unsigned short f2bf(float f) {
    unsigned int u = __float_as_uint(f);
    u += 0x7fffu + ((u >> 16) & 1u);
    return (unsigned short)(u >> 16);
}

__device__ __forceinline__ void gl_lds16(const void* g, void* l) {
    __builtin_amdgcn_global_load_lds(
        (const __attribute__((address_space(1))) unsigned int*)(uintptr_t)(g),
        (__attribute__((address_space(3))) unsigned int*)(unsigned int)(uintptr_t)(l),
        16, 0, 0);
}

// ---------------- standalone transpose+convert (fallback path only) ----------------
__global__ __launch_bounds__(256) void transpose_convert_k(
    const float* __restrict__ src, unsigned short* __restrict__ dst, int K, int N) {
    __shared__ float t[32][33];
    int kt = blockIdx.y * 32, nt = blockIdx.x * 32;
    int tx = threadIdx.x & 31, ty = threadIdx.x >> 5;
#pragma unroll
    for (int i = 0; i < 4; i++)
        t[ty + i * 8][tx] = src[(size_t)(kt + ty + i * 8) * N + nt + tx];
    __syncthreads();
#pragma unroll
    for (int i = 0; i < 4; i++)
        dst[(size_t)(nt + ty + i * 8) * K + kt + tx] = f2bf(t[tx][ty + i * 8]);
}

// ---------------- fused prep: embed+LN0 | 64x64 transpose of W0 | W1 | fc_w (R12) ----------------
__global__ __launch_bounds__(256) void prep_k(
    const int* __restrict__ ids, const float* __restrict__ emb,
    const float* __restrict__ gam, const float* __restrict__ bet,
    float* __restrict__ xres, unsigned short* __restrict__ xw,
    const float* __restrict__ W0, unsigned short* __restrict__ wt0,
    const float* __restrict__ W1, unsigned short* __restrict__ wt1,
    const float* __restrict__ fcw, unsigned short* __restrict__ fcwt) {
    __shared__ float t[64][69];
    int vb = blockIdx.x;
    int tid = threadIdx.x;
    if (vb < 2048) {
        int row = vb * 4 + (tid >> 6);
        int lane = tid & 63;
        const float4* src = (const float4*)(emb + (size_t)ids[row] * EMB_);
        float v[8];
        *(float4*)(v) = src[lane * 2];
        *(float4*)(v + 4) = src[lane * 2 + 1];
        float s = 0.f, s2 = 0.f;
#pragma unroll
        for (int j = 0; j < 8; j++) { s += v[j]; s2 += v[j] * v[j]; }
#pragma unroll
        for (int off = 1; off < 64; off <<= 1) {
            s += __shfl_xor(s, off);
            s2 += __shfl_xor(s2, off);
        }
        float mu = s * (1.f / EMB_);
        float var = fmaxf(s2 * (1.f / EMB_) - mu * mu, 0.f);
        float rstd = rsqrtf(var + 1e-5f);
        float4* xr = (float4*)(xres + (size_t)row * EMB_);
        xr[lane * 2] = *(float4*)(v);
        xr[lane * 2 + 1] = *(float4*)(v + 4);
        u16x8 o;
#pragma unroll
        for (int j = 0; j < 8; j++) {
            int c = lane * 8 + j;
            o[j] = f2bf((v[j] - mu) * rstd * gam[c] + bet[c]);
        }
        *(u16x8*)(xw + (size_t)row * EMB_ + lane * 8) = o;
        return;
    }
    vb -= 2048;
    const float* src;
    unsigned short* dst;
    int N;
    if (vb < 128)        { src = W0;  dst = wt0;  N = 1024; }
    else if (vb < 256)   { vb -= 128; src = W1;  dst = wt1;  N = 1024; }
    else                 { vb -= 256; src = fcw; dst = fcwt; N = VOCAB_; }
    int ntiles = N >> 6;
    int ktile = vb / ntiles, ntile = vb - ktile * ntiles;
    int kt = ktile << 6, nt = ntile << 6;
    int tx = tid & 15, ty = tid >> 4;
#pragma unroll
    for (int i = 0; i < 4; i++) {
        int r = ty + 16 * i;
        float4 v = *(const float4*)(src + (size_t)(kt + r) * N + nt + tx * 4);
        t[r][tx * 4 + 0] = v.x;
        t[r][tx * 4 + 1] = v.y;
        t[r][tx * 4 + 2] = v.z;
        t[r][tx * 4 + 3] = v.w;
    }
    __syncthreads();
#pragma unroll
    for (int i = 0; i < 4; i++) {
        int d = ty + 16 * i;
        short4v o;
#pragma unroll
        for (int j = 0; j < 4; j++)
            o[j] = (short)f2bf(t[tx * 4 + j][d]);
        *(short4v*)(dst + (size_t)(nt + d) * 512 + kt + tx * 4) = o;
    }
}

// ---------------- LayerNorm of xsrc -> bf16 xw ----------------
__global__ __launch_bounds__(256) void ln_k(
    const float* __restrict__ xsrc,
    const float* __restrict__ gam, const float* __restrict__ bet,
    unsigned short* __restrict__ xw, float eps) {
    int row = blockIdx.x * 4 + (threadIdx.x >> 6);
    int lane = threadIdx.x & 63;
    const float4* src = (const float4*)(xsrc + (size_t)row * HID_);
    float v[8];
    *(float4*)(v) = src[lane * 2];
    *(float4*)(v + 4) = src[lane * 2 + 1];
    float s = 0.f, s2 = 0.f;
#pragma unroll
    for (int j = 0; j < 8; j++) { s += v[j]; s2 += v[j] * v[j]; }
#pragma unroll
    for (int off = 1; off < 64; off <<= 1) {
        s += __shfl_xor(s, off);
        s2 += __shfl_xor(s2, off);
    }
    float mu = s * (1.f / HID_);
    float var = fmaxf(s2 * (1.f / HID_) - mu * mu, 0.f);
    float rstd = rsqrtf(var + eps);
    u16x8 o;
#pragma unroll
    for (int j = 0; j < 8; j++) {
        int c = lane * 8 + j;
        o[j] = f2bf((v[j] - mu) * rstd * gam[c] + bet[c]);
    }
    *(u16x8*)(xw + (size_t)row * HID_ + lane * 8) = o;
}

// ---------------- layer GEMM: 128x128 tile, BK=64, 4 waves; LDS-transpose epilogue (R4) ----------------
__global__ __launch_bounds__(256) void gemm_bf16_k(
    const unsigned short* __restrict__ A, const unsigned short* __restrict__ Bt,
    float* __restrict__ C, int M, int N, int K) {
    __shared__ unsigned short lA[128 * 64];
    __shared__ unsigned short lB[128 * 64];
    __shared__ float eT[4][16 * 68];
    int tid = threadIdx.x;
    int w = tid >> 6, l = tid & 63;
    int m0 = blockIdx.y * 128, n0 = blockIdx.x * 128;
    int wm = w >> 1, wn = w & 1;
    f32x4 acc[4][4] = {};

    int rIn = l >> 3;
    int cOff = (l & 7) * 8;

    for (int k0 = 0; k0 < K; k0 += 64) {
#pragma unroll
        for (int i = 0; i < 4; i++) {
            int c = w * 4 + i;
            gl_lds16(A + (size_t)(m0 + c * 8 + rIn) * K + k0 + cOff, &lA[c * 512]);
            gl_lds16(Bt + (size_t)(n0 + c * 8 + rIn) * K + k0 + cOff, &lB[c * 512]);
        }
        asm volatile("s_waitcnt vmcnt(0)" ::: "memory");
        __syncthreads();

        const unsigned short* pa = lA + ((size_t)(wm * 64 + (l & 15)) * 64) + ((l >> 4) * 8);
        const unsigned short* pb = lB + ((size_t)(wn * 64 + (l & 15)) * 64) + ((l >> 4) * 8);
#pragma unroll
        for (int kk = 0; kk < 2; kk++) {
            short8 af[4], bfr[4];
#pragma unroll
            for (int m = 0; m < 4; m++) af[m] = *(const short8*)(pa + m * 16 * 64 + kk * 32);
#pragma unroll
            for (int n = 0; n < 4; n++) bfr[n] = *(const short8*)(pb + n * 16 * 64 + kk * 32);
#pragma unroll
            for (int m = 0; m < 4; m++)
#pragma unroll
                for (int n = 0; n < 4; n++)
                    acc[m][n] = __builtin_amdgcn_mfma_f32_16x16x32_bf16(af[m], bfr[n], acc[m][n], 0, 0, 0);
        }
        __syncthreads();
    }

    float* ep = eT[w];
    int rl = l >> 4, slot = l & 15;
    int rbase = m0 + wm * 64, cbase = n0 + wn * 64;
#pragma unroll
    for (int mf = 0; mf < 4; ++mf) {
#pragma unroll
        for (int nf = 0; nf < 4; ++nf)
#pragma unroll
            for (int j = 0; j < 4; ++j)
                ep[(rl * 4 + j) * 68 + nf * 16 + slot] = acc[mf][nf][j];
        asm volatile("s_waitcnt lgkmcnt(0)" ::: "memory");
#pragma unroll
        for (int p = 0; p < 4; ++p) {
            int r = p * 4 + rl;
            f32x4 vv = *(const f32x4*)(ep + r * 68 + slot * 4);
            *(f32x4*)(C + (size_t)(rbase + mf * 16 + r) * N + cbase + slot * 4) = vv;
        }
        asm volatile("s_waitcnt lgkmcnt(0)" ::: "memory");
    }
}

// ---------------- persistent final GEMM (R8/R12 + staggered tile start) ----------------
// Tile-start rotation: block bn begins its 16-tile walk at tile (bn & 15), so the 125
// blocks of a bm-group are spread across all 16 tile phases -> epilogue write bursts and
// staging read bursts are uniform in time instead of synchronized spikes.
__device__ __forceinline__ void stageP(
    const unsigned short* __restrict__ A, const unsigned short* __restrict__ Bt,
    int bmbase, int bn, int H, char* smem, int r0, int c0, unsigned wq) {
    if (H >= 4 * NT_TOT) return;
    int T = H >> 2, j = H & 3;
    int ti = ((T >> 3) + (bn & 15)) & 15;     // rotated tile index
    int kt = T & 7;
    const unsigned short* src = (j < 2) ? A : Bt;
    int row0 = ((j < 2) ? ((bmbase + ti) << 8) : (bn << 8)) + ((j & 1) << 7);
    unsigned tb = ((unsigned)(T & 1) << 16) | ((unsigned)(j >> 1) << 15) | ((unsigned)(j & 1) << 14);
    const unsigned short* g0 = src + (size_t)(row0 + r0) * FK_ + ((kt << 6) + c0);
    gl_lds16(g0, (unsigned short*)(smem + tb + wq));
    gl_lds16(g0 + (size_t)64 * FK_, (unsigned short*)(smem + tb + 8192 + wq));
}

#define MIDBAR() __builtin_amdgcn_s_barrier()
#define ENDBAR() do { asm volatile("s_waitcnt lgkmcnt(0)" ::: "memory"); \
                      asm volatile("s_barrier" ::: "memory"); } while (0)

#define PHASE_MFMA(AF, BF, MO, NO)                                                  \
    do {                                                                            \
        __builtin_amdgcn_s_setprio(1);                                             \
        _Pragma("unroll") for (int mf = 0; mf < 4; ++mf)                            \
        _Pragma("unroll") for (int nf = 0; nf < 2; ++nf)                            \
        _Pragma("unroll") for (int ks = 0; ks < 2; ++ks)                            \
            acc[(MO) + mf][(NO) + nf] = __builtin_amdgcn_mfma_f32_16x16x32_bf16(    \
                AF[mf][ks], BF[nf][ks], acc[(MO) + mf][(NO) + nf], 0, 0, 0);        \
        __builtin_amdgcn_s_setprio(0);                                             \
    } while (0)

__global__ __launch_bounds__(512, 2) void gemmP_k(
    const unsigned short* __restrict__ A, const unsigned short* __restrict__ Bt,
    const float* __restrict__ bias, float* __restrict__ C) {
    extern __shared__ char smem[];
    int tid = threadIdx.x;
    int w = tid >> 6, l = tid & 63;
    int wm = w >> 2, wn = w & 3;

    int bn = blockIdx.x % NBN_F;
    int bmbase = (blockIdx.x / NBN_F) * OT_PER_BLK;

    int r0 = ((w >> 1) << 4) + (l >> 2);
    int c0 = ((w & 1) << 5) + (((l & 3) << 3) ^ ((l & 32) ? 16 : 0));
    unsigned wq = (unsigned)(w << 10);

    unsigned rowpart = (unsigned)(((l & 15) << 6) + (((((l >> 4) << 3)) ^ ((l & 8) ? 16 : 0)) << 1));
    unsigned aoff = ((unsigned)wm << 14) + rowpart;
    unsigned boff = 32768u + ((unsigned)wn << 13) + rowpart;

    f32x4 acc[8][4] = {};

    if (tid < 64) {
        f32x4 bv = *(const f32x4*)(bias + (bn << 8) + (tid << 2));
        *(f32x4*)(smem + BIAS_OFF + (tid << 4)) = bv;
    }
    asm volatile("s_waitcnt vmcnt(0) lgkmcnt(0)" ::: "memory");
    asm volatile("" ::: "memory");

    stageP(A, Bt, bmbase, bn, 0, smem, r0, c0, wq); asm volatile("" ::: "memory");
    stageP(A, Bt, bmbase, bn, 1, smem, r0, c0, wq); asm volatile("" ::: "memory");
    stageP(A, Bt, bmbase, bn, 2, smem, r0, c0, wq); asm volatile("" ::: "memory");
    stageP(A, Bt, bmbase, bn, 3, smem, r0, c0, wq); asm volatile("" ::: "memory");
    stageP(A, Bt, bmbase, bn, 4, smem, r0, c0, wq); asm volatile("" ::: "memory");
    stageP(A, Bt, bmbase, bn, 5, smem, r0, c0, wq);
    asm volatile("s_waitcnt vmcnt(4)" ::: "memory");
    asm volatile("s_barrier" ::: "memory");

    for (int T = 0; T < NT_TOT; ++T) {
        const char* pA = smem + (((unsigned)(T & 1)) << 16) + aoff;
        const char* pB = smem + (((unsigned)(T & 1)) << 16) + boff;
        short8 A0[4][2], A1[4][2], B0[2][2], B1[2][2];

#pragma unroll
        for (int mf = 0; mf < 4; ++mf)
#pragma unroll
            for (int ks = 0; ks < 2; ++ks)
                A0[mf][ks] = *(const short8*)(pA + mf * 2048 + ks * 1024);
#pragma unroll
        for (int nf = 0; nf < 2; ++nf)
#pragma unroll
            for (int ks = 0; ks < 2; ++ks)
                B0[nf][ks] = *(const short8*)(pB + nf * 2048 + ks * 1024);
        stageP(A, Bt, bmbase, bn, 4 * T + 6, smem, r0, c0, wq);
        MIDBAR();
        PHASE_MFMA(A0, B0, 0, 0);
        ENDBAR();

#pragma unroll
        for (int mf = 0; mf < 4; ++mf)
#pragma unroll
            for (int ks = 0; ks < 2; ++ks)
                A1[mf][ks] = *(const short8*)(pA + (4 + mf) * 2048 + ks * 1024);
#pragma unroll
        for (int nf = 0; nf < 2; ++nf)
#pragma unroll
            for (int ks = 0; ks < 2; ++ks)
                B1[nf][ks] = *(const short8*)(pB + (2 + nf) * 2048 + ks * 1024);
        stageP(A, Bt, bmbase, bn, 4 * T + 7, smem, r0, c0, wq);
        MIDBAR();
        PHASE_MFMA(A1, B0, 4, 0);
        ENDBAR();

        stageP(A, Bt, bmbase, bn, 4 * T + 8, smem, r0, c0, wq);
        MIDBAR();
        PHASE_MFMA(A1, B1, 4, 2);
        ENDBAR();

        stageP(A, Bt, bmbase, bn, 4 * T + 9, smem, r0, c0, wq);
        if (T < NT_TOT - 2)       { asm volatile("s_waitcnt vmcnt(4)" ::: "memory"); }
        else if (T == NT_TOT - 2) { asm volatile("s_waitcnt vmcnt(0)" ::: "memory"); }
        MIDBAR();
        PHASE_MFMA(A0, B1, 0, 2);
        ENDBAR();

        if ((T & 7) == 7) {
            int bm = bmbase + (((T >> 3) + (bn & 15)) & 15);   // rotated (matches stageP)
            float* ep = (float*)(smem + EP_OFF) + w * (16 * 40);
            const float* bls = (const float*)(smem + BIAS_OFF);
            int rl = l >> 4, slot = l & 15;
            int rbase = (bm << 8) + (wm << 7);
            int cbase = (bn << 8) + (wn << 6);
            float bs[4];
#pragma unroll
            for (int nf = 0; nf < 4; ++nf) bs[nf] = bls[(wn << 6) + nf * 16 + slot];
#pragma unroll
            for (int mf = 0; mf < 8; ++mf) {
#pragma unroll
                for (int nfp = 0; nfp < 2; ++nfp) {
#pragma unroll
                    for (int nf2 = 0; nf2 < 2; ++nf2)
#pragma unroll
                        for (int j = 0; j < 4; ++j)
                            ep[(rl * 4 + j) * 40 + nf2 * 16 + slot] =
                                acc[mf][nfp * 2 + nf2][j] + bs[nfp * 2 + nf2];
                    asm volatile("s_waitcnt lgkmcnt(0)" ::: "memory");
#pragma unroll
                    for (int p = 0; p < 2; ++p) {
                        int r = p * 8 + (l >> 3);
                        f32x4 vv = *(const f32x4*)(ep + r * 40 + (l & 7) * 4);
                        __builtin_nontemporal_store(vv,
                            (f32x4*)(C + (size_t)(rbase + mf * 16 + r) * VOCAB_ +
                                     cbase + nfp * 32 + (l & 7) * 4));
                    }
                    asm volatile("s_waitcnt lgkmcnt(0)" ::: "memory");
                }
#pragma unroll
                for (int nf = 0; nf < 4; ++nf) acc[mf][nf] = f32x4{0.f, 0.f, 0.f, 0.f};
            }
        }
    }
}

// ---------------- minGRU scan (R8: CHUNK=64) ----------------
__device__ __forceinline__ void gate_terms(float k, float hp, float& a, float& b) {
    float z = 1.f / (1.f + __expf(-k));
    a = 1.f - z;
    float g = (hp >= 0.f) ? (hp + 0.5f) : (1.f / (1.f + __expf(-hp)));
    b = z * g;
}

__global__ __launch_bounds__(256) void scan1_k(
    const float* __restrict__ proj, float* __restrict__ Ach, float* __restrict__ Bch) {
    int t = blockIdx.x * 256 + threadIdx.x;
    int h = t & (HID_ - 1);
    int bc = t >> 9;
    int b = bc >> 5, c = bc & (NCHUNK - 1);
    const float* p = proj + ((size_t)(b * S_ + c * CHUNK)) * (2 * HID_) + h;
    float A = 1.f, H = 0.f;
#pragma unroll 4
    for (int s = 0; s < CHUNK; s++) {
        float k = p[(size_t)s * (2 * HID_)];
        float hp = p[(size_t)s * (2 * HID_) + HID_];
        float a, bb;
        gate_terms(k, hp, a, bb);
        H = a * H + bb;
        A *= a;
    }
    Ach[t] = A;
    Bch[t] = H;
}

__global__ __launch_bounds__(256) void scan23_k(
    const float* __restrict__ proj, const float* __restrict__ Ach,
    const float* __restrict__ Bch, float* __restrict__ xres) {
    int t = blockIdx.x * 256 + threadIdx.x;
    int h = t & (HID_ - 1);
    int bc = t >> 9;
    int b = bc >> 5, c = bc & (NCHUNK - 1);
    float H = 0.f;
    for (int cp = 0; cp < c; cp++) {
        int idx = (b * NCHUNK + cp) * HID_ + h;
        H = Ach[idx] * H + Bch[idx];
    }
    const float* p = proj + ((size_t)(b * S_ + c * CHUNK)) * (2 * HID_) + h;
    float* x = xres + ((size_t)(b * S_ + c * CHUNK)) * HID_ + h;
#pragma unroll 4
    for (int s = 0; s < CHUNK; s++) {
        float k = p[(size_t)s * (2 * HID_)];
        float hp = p[(size_t)s * (2 * HID_) + HID_];
        float a, bb;
        gate_terms(k, hp, a, bb);
        H = a * H + bb;
        x[(size_t)s * HID_] += H;
    }
}

// ---------------- launch ----------------
extern "C" void kernel_launch(void* const* d_in, const int* in_sizes, int n_in,
                              void* d_out, int out_size, void* d_ws, size_t ws_size,
                              hipStream_t stream) {
    const int* ids = (const int*)d_in[0];
    const float* emb = (const float*)d_in[1];
    const float* W0 = (const float*)d_in[2];
    const float* W1 = (const float*)d_in[3];
    const float* ln0_g = (const float*)d_in[4];
    const float* ln0_b = (const float*)d_in[5];
    const float* ln1_g = (const float*)d_in[6];
    const float* ln1_b = (const float*)d_in[7];
    const float* lnf_g = (const float*)d_in[8];
    const float* lnf_b = (const float*)d_in[9];
    const float* fc_w = (const float*)d_in[10];
    const float* fc_b = (const float*)d_in[11];
    float* out = (float*)d_out;

    (void)hipFuncSetAttribute((const void*)gemmP_k,
                              hipFuncAttributeMaxDynamicSharedMemorySize, SMEM_TOT);

    char* ws = (char*)d_ws;
    const size_t OFF_XW   = 0;
    const size_t OFF_PROJ = 8388608;
    const size_t OFF_XRES = OFF_PROJ + 33554432;
    const size_t OFF_WT0  = OFF_XRES + 16777216;
    const size_t OFF_WT1  = OFF_WT0 + 1048576;
    const size_t OFF_SA   = OFF_WT1 + 1048576;
    const size_t OFF_SB   = OFF_SA + 262144;
    const size_t OFF_FCWT = OFF_SB + 262144;
    const size_t NEED_BIG = OFF_FCWT + 32768000;

    unsigned short* xw  = (unsigned short*)(ws + OFF_XW);
    float* proj         = (float*)(ws + OFF_PROJ);
    float* xres         = (float*)(ws + OFF_XRES);
    unsigned short* wt0 = (unsigned short*)(ws + OFF_WT0);
    unsigned short* wt1 = (unsigned short*)(ws + OFF_WT1);
    float* sA = (float*)(ws + OFF_SA);
    float* sB = (float*)(ws + OFF_SB);

    bool big = ws_size >= NEED_BIG;
    unsigned short* fcwt = big ? (unsigned short*)(ws + OFF_FCWT)
                               : (unsigned short*)(ws + OFF_PROJ);

    if (big) {
        prep_k<<<2048 + 128 + 128 + 4000, 256, 0, stream>>>(
            ids, emb, ln0_g, ln0_b, xres, xw, W0, wt0, W1, wt1, fc_w, fcwt);
    } else {
        prep_k<<<2048 + 128 + 128, 256, 0, stream>>>(
            ids, emb, ln0_g, ln0_b, xres, xw, W0, wt0, W1, wt1, fc_w, wt0);
    }

    // layer 0
    gemm_bf16_k<<<dim3(1024 / 128, ROWS / 128), 256, 0, stream>>>(xw, wt0, proj, ROWS, 1024, 512);
    scan1_k<<<65536 / 256, 256, 0, stream>>>(proj, sA, sB);
    scan23_k<<<65536 / 256, 256, 0, stream>>>(proj, sA, sB, xres);

    // layer 1
    ln_k<<<ROWS / 4, 256, 0, stream>>>(xres, ln1_g, ln1_b, xw, 1e-5f);
    gemm_bf16_k<<<dim3(1024 / 128, ROWS / 128), 256, 0, stream>>>(xw, wt1, proj, ROWS, 1024, 512);
    scan1_k<<<65536 / 256, 256, 0, stream>>>(proj, sA, sB);
    scan23_k<<<65536 / 256, 256, 0, stream>>>(proj, sA, sB, xres);

    // final LN (eps=0.0) + logits
    ln_k<<<ROWS / 4, 256, 0, stream>>>(xres, lnf_g, lnf_b, xw, 0.0f);
    if (!big) {
        transpose_convert_k<<<dim3(VOCAB_ / 32, 512 / 32), 256, 0, stream>>>(fc_w, fcwt, 512, VOCAB_);
    }
    gemmP_k<<<NBLK_F, 512, SMEM_TOT, stream>>>(xw, fcwt, fc_b, out);
}

// Round 15
// 536.095 us; speedup vs baseline: 1.0849x; 1.0255x over previous
//
#include <hip/hip_runtime.h>

typedef __attribute__((ext_vector_type(8))) short short8;
typedef __attribute__((ext_vector_type(4))) float f32x4;
typedef __attribute__((ext_vector_type(8))) unsigned short u16x8;

#define B_ 4
#define S_ 2048
#define EMB_ 512
#define HID_ 512
#define VOCAB_ 32000
#define ROWS (B_ * S_)          // 8192
#define NCHUNK 32
#define CHUNK 64                // NCHUNK*CHUNK == S_

// persistent final GEMM geometry
#define FK_ 512
#define NBN_F 125               // 32000/256
#define OT_PER_BLK 16           // 16 bm-tiles per block, one bn per block
#define NBLK_F (NBN_F * 2)      // 250 = (32/16) bm-groups x 125 bn
#define NT_TOT (OT_PER_BLK * 8) // 128 k-tiles per block
#define EP_OFF 131072           // epilogue scratch (8 waves x 16 x 40 f32 = 20480 B)
#define BIAS_OFF (EP_OFF + 20480)
#define SMEM_TOT (BIAS_OFF + 1024)   // 152576

__device__ __forceinline__ unsigned short f2bf(float f) {
    unsigned int u = __float_as_uint(f);
    u += 0x7fffu + ((u >> 16) & 1u);
    return (unsigned short)(u >> 16);
}

__device__ __forceinline__ void gl_lds16(const unsigned short* g, unsigned short* l) {
    __builtin_amdgcn_global_load_lds(
        (const __attribute__((address_space(1))) unsigned int*)(uintptr_t)(g),
        (__attribute__((address_space(3))) unsigned int*)(unsigned int)(uintptr_t)(l),
        16, 0, 0);
}

// ---------------- standalone transpose+convert (fallback path only) ----------------
__global__ __launch_bounds__(256) void transpose_convert_k(
    const float* __restrict__ src, unsigned short* __restrict__ dst, int K, int N) {
    __shared__ float t[32][33];
    int kt = blockIdx.y * 32, nt = blockIdx.x * 32;
    int tx = threadIdx.x & 31, ty = threadIdx.x >> 5;
#pragma unroll
    for (int i = 0; i < 4; i++)
        t[ty + i * 8][tx] = src[(size_t)(kt + ty + i * 8) * N + nt + tx];
    __syncthreads();
#pragma unroll
    for (int i = 0; i < 4; i++)
        dst[(size_t)(nt + ty + i * 8) * K + kt + tx] = f2bf(t[tx][ty + i * 8]);
}

// ---------------- fused prep: embed+LN0 | transpose W0 | W1 | fc_w ----------------
__global__ __launch_bounds__(256) void prep_k(
    const int* __restrict__ ids, const float* __restrict__ emb,
    const float* __restrict__ gam, const float* __restrict__ bet,
    float* __restrict__ xres, unsigned short* __restrict__ xw,
    const float* __restrict__ W0, unsigned short* __restrict__ wt0,
    const float* __restrict__ W1, unsigned short* __restrict__ wt1,
    const float* __restrict__ fcw, unsigned short* __restrict__ fcwt) {
    __shared__ float t[32][33];
    int vb = blockIdx.x;
    int tid = threadIdx.x;
    if (vb < 2048) {
        int row = vb * 4 + (tid >> 6);
        int lane = tid & 63;
        const float4* src = (const float4*)(emb + (size_t)ids[row] * EMB_);
        float v[8];
        *(float4*)(v) = src[lane * 2];
        *(float4*)(v + 4) = src[lane * 2 + 1];
        float s = 0.f, s2 = 0.f;
#pragma unroll
        for (int j = 0; j < 8; j++) { s += v[j]; s2 += v[j] * v[j]; }
#pragma unroll
        for (int off = 1; off < 64; off <<= 1) {
            s += __shfl_xor(s, off);
            s2 += __shfl_xor(s2, off);
        }
        float mu = s * (1.f / EMB_);
        float var = fmaxf(s2 * (1.f / EMB_) - mu * mu, 0.f);
        float rstd = rsqrtf(var + 1e-5f);
        float4* xr = (float4*)(xres + (size_t)row * EMB_);
        xr[lane * 2] = *(float4*)(v);
        xr[lane * 2 + 1] = *(float4*)(v + 4);
        u16x8 o;
#pragma unroll
        for (int j = 0; j < 8; j++) {
            int c = lane * 8 + j;
            o[j] = f2bf((v[j] - mu) * rstd * gam[c] + bet[c]);
        }
        *(u16x8*)(xw + (size_t)row * EMB_ + lane * 8) = o;
        return;
    }
    vb -= 2048;
    const float* src;
    unsigned short* dst;
    int N;
    if (vb < 512)        { src = W0;  dst = wt0;  N = 1024; }
    else if (vb < 1024)  { vb -= 512;  src = W1;  dst = wt1;  N = 1024; }
    else                 { vb -= 1024; src = fcw; dst = fcwt; N = VOCAB_; }
    int ntiles = N >> 5;
    int ktile = vb / ntiles, ntile = vb - ktile * ntiles;
    int kt = ktile << 5, nt = ntile << 5;
    int tx = tid & 31, ty = tid >> 5;
#pragma unroll
    for (int i = 0; i < 4; i++)
        t[ty + i * 8][tx] = src[(size_t)(kt + ty + i * 8) * N + nt + tx];
    __syncthreads();
#pragma unroll
    for (int i = 0; i < 4; i++)
        dst[(size_t)(nt + ty + i * 8) * 512 + kt + tx] = f2bf(t[tx][ty + i * 8]);
}

// ---------------- LayerNorm of xsrc -> bf16 xw ----------------
__global__ __launch_bounds__(256) void ln_k(
    const float* __restrict__ xsrc,
    const float* __restrict__ gam, const float* __restrict__ bet,
    unsigned short* __restrict__ xw, float eps) {
    int row = blockIdx.x * 4 + (threadIdx.x >> 6);
    int lane = threadIdx.x & 63;
    const float4* src = (const float4*)(xsrc + (size_t)row * HID_);
    float v[8];
    *(float4*)(v) = src[lane * 2];
    *(float4*)(v + 4) = src[lane * 2 + 1];
    float s = 0.f, s2 = 0.f;
#pragma unroll
    for (int j = 0; j < 8; j++) { s += v[j]; s2 += v[j] * v[j]; }
#pragma unroll
    for (int off = 1; off < 64; off <<= 1) {
        s += __shfl_xor(s, off);
        s2 += __shfl_xor(s2, off);
    }
    float mu = s * (1.f / HID_);
    float var = fmaxf(s2 * (1.f / HID_) - mu * mu, 0.f);
    float rstd = rsqrtf(var + eps);
    u16x8 o;
#pragma unroll
    for (int j = 0; j < 8; j++) {
        int c = lane * 8 + j;
        o[j] = f2bf((v[j] - mu) * rstd * gam[c] + bet[c]);
    }
    *(u16x8*)(xw + (size_t)row * HID_ + lane * 8) = o;
}

// ---------------- layer GEMM: 128x128 tile, BK=64, 4 waves; LDS-transpose epilogue (R4) ----------------
__global__ __launch_bounds__(256) void gemm_bf16_k(
    const unsigned short* __restrict__ A, const unsigned short* __restrict__ Bt,
    float* __restrict__ C, int M, int N, int K) {
    __shared__ unsigned short lA[128 * 64];
    __shared__ unsigned short lB[128 * 64];
    __shared__ float eT[4][16 * 68];
    int tid = threadIdx.x;
    int w = tid >> 6, l = tid & 63;
    int m0 = blockIdx.y * 128, n0 = blockIdx.x * 128;
    int wm = w >> 1, wn = w & 1;
    f32x4 acc[4][4] = {};

    int rIn = l >> 3;
    int cOff = (l & 7) * 8;

    for (int k0 = 0; k0 < K; k0 += 64) {
#pragma unroll
        for (int i = 0; i < 4; i++) {
            int c = w * 4 + i;
            gl_lds16(A + (size_t)(m0 + c * 8 + rIn) * K + k0 + cOff, &lA[c * 512]);
            gl_lds16(Bt + (size_t)(n0 + c * 8 + rIn) * K + k0 + cOff, &lB[c * 512]);
        }
        asm volatile("s_waitcnt vmcnt(0)" ::: "memory");
        __syncthreads();

        const unsigned short* pa = lA + ((size_t)(wm * 64 + (l & 15)) * 64) + ((l >> 4) * 8);
        const unsigned short* pb = lB + ((size_t)(wn * 64 + (l & 15)) * 64) + ((l >> 4) * 8);
#pragma unroll
        for (int kk = 0; kk < 2; kk++) {
            short8 af[4], bfr[4];
#pragma unroll
            for (int m = 0; m < 4; m++) af[m] = *(const short8*)(pa + m * 16 * 64 + kk * 32);
#pragma unroll
            for (int n = 0; n < 4; n++) bfr[n] = *(const short8*)(pb + n * 16 * 64 + kk * 32);
#pragma unroll
            for (int m = 0; m < 4; m++)
#pragma unroll
                for (int n = 0; n < 4; n++)
                    acc[m][n] = __builtin_amdgcn_mfma_f32_16x16x32_bf16(af[m], bfr[n], acc[m][n], 0, 0, 0);
        }
        __syncthreads();
    }

    float* ep = eT[w];
    int rl = l >> 4, slot = l & 15;
    int rbase = m0 + wm * 64, cbase = n0 + wn * 64;
#pragma unroll
    for (int mf = 0; mf < 4; ++mf) {
#pragma unroll
        for (int nf = 0; nf < 4; ++nf)
#pragma unroll
            for (int j = 0; j < 4; ++j)
                ep[(rl * 4 + j) * 68 + nf * 16 + slot] = acc[mf][nf][j];
        asm volatile("s_waitcnt lgkmcnt(0)" ::: "memory");
#pragma unroll
        for (int p = 0; p < 4; ++p) {
            int r = p * 4 + rl;
            f32x4 vv = *(const f32x4*)(ep + r * 68 + slot * 4);
            *(f32x4*)(C + (size_t)(rbase + mf * 16 + r) * N + cbase + slot * 4) = vv;
        }
        asm volatile("s_waitcnt lgkmcnt(0)" ::: "memory");
    }
}

// ---------------- persistent final GEMM: 256x256, 8-phase, 16 tiles/block, col-major ----------------
__device__ __forceinline__ void stageP(
    const unsigned short* __restrict__ A, const unsigned short* __restrict__ Bt,
    int bmbase, int bn, int H, char* smem, int r0, int c0, unsigned wq) {
    if (H >= 4 * NT_TOT) return;
    int T = H >> 2, j = H & 3;
    int ti = T >> 3, kt = T & 7;
    const unsigned short* src = (j < 2) ? A : Bt;
    int row0 = ((j < 2) ? ((bmbase + ti) << 8) : (bn << 8)) + ((j & 1) << 7);
    unsigned tb = ((unsigned)(T & 1) << 16) | ((unsigned)(j >> 1) << 15) | ((unsigned)(j & 1) << 14);
    const unsigned short* g0 = src + (size_t)(row0 + r0) * FK_ + ((kt << 6) + c0);
    gl_lds16(g0, (unsigned short*)(smem + tb + wq));
    gl_lds16(g0 + (size_t)64 * FK_, (unsigned short*)(smem + tb + 8192 + wq));
}

#define MIDBAR() __builtin_amdgcn_s_barrier()
#define ENDBAR() do { asm volatile("s_waitcnt lgkmcnt(0)" ::: "memory"); \
                      asm volatile("s_barrier" ::: "memory"); } while (0)

#define PHASE_MFMA(AF, BF, MO, NO)                                                  \
    do {                                                                            \
        __builtin_amdgcn_s_setprio(1);                                             \
        _Pragma("unroll") for (int mf = 0; mf < 4; ++mf)                            \
        _Pragma("unroll") for (int nf = 0; nf < 2; ++nf)                            \
        _Pragma("unroll") for (int ks = 0; ks < 2; ++ks)                            \
            acc[(MO) + mf][(NO) + nf] = __builtin_amdgcn_mfma_f32_16x16x32_bf16(    \
                AF[mf][ks], BF[nf][ks], acc[(MO) + mf][(NO) + nf], 0, 0, 0);        \
        __builtin_amdgcn_s_setprio(0);                                             \
    } while (0)

__global__ __launch_bounds__(512, 2) void gemmP_k(
    const unsigned short* __restrict__ A, const unsigned short* __restrict__ Bt,
    const float* __restrict__ bias, float* __restrict__ C) {
    extern __shared__ char smem[];
    int tid = threadIdx.x;
    int w = tid >> 6, l = tid & 63;
    int wm = w >> 2, wn = w & 3;

    int bn = blockIdx.x % NBN_F;
    int bmbase = (blockIdx.x / NBN_F) * OT_PER_BLK;

    int r0 = ((w >> 1) << 4) + (l >> 2);
    int c0 = ((w & 1) << 5) + (((l & 3) << 3) ^ ((l & 32) ? 16 : 0));
    unsigned wq = (unsigned)(w << 10);

    unsigned rowpart = (unsigned)(((l & 15) << 6) + (((((l >> 4) << 3)) ^ ((l & 8) ? 16 : 0)) << 1));
    unsigned aoff = ((unsigned)wm << 14) + rowpart;
    unsigned boff = 32768u + ((unsigned)wn << 13) + rowpart;

    f32x4 acc[8][4] = {};

    // stage block-constant bias into LDS BEFORE any pipeline staging (keeps vmcnt ledger clean)
    if (tid < 64) {
        f32x4 bv = *(const f32x4*)(bias + (bn << 8) + (tid << 2));
        *(f32x4*)(smem + BIAS_OFF + (tid << 4)) = bv;
    }
    asm volatile("s_waitcnt vmcnt(0) lgkmcnt(0)" ::: "memory");
    asm volatile("" ::: "memory");

    stageP(A, Bt, bmbase, bn, 0, smem, r0, c0, wq); asm volatile("" ::: "memory");
    stageP(A, Bt, bmbase, bn, 1, smem, r0, c0, wq); asm volatile("" ::: "memory");
    stageP(A, Bt, bmbase, bn, 2, smem, r0, c0, wq); asm volatile("" ::: "memory");
    stageP(A, Bt, bmbase, bn, 3, smem, r0, c0, wq); asm volatile("" ::: "memory");
    stageP(A, Bt, bmbase, bn, 4, smem, r0, c0, wq); asm volatile("" ::: "memory");
    stageP(A, Bt, bmbase, bn, 5, smem, r0, c0, wq);
    asm volatile("s_waitcnt vmcnt(4)" ::: "memory");
    asm volatile("s_barrier" ::: "memory");

    for (int T = 0; T < NT_TOT; ++T) {
        const char* pA = smem + (((unsigned)(T & 1)) << 16) + aoff;
        const char* pB = smem + (((unsigned)(T & 1)) << 16) + boff;
        short8 A0[4][2], A1[4][2], B0[2][2], B1[2][2];

        // phase 0
#pragma unroll
        for (int mf = 0; mf < 4; ++mf)
#pragma unroll
            for (int ks = 0; ks < 2; ++ks)
                A0[mf][ks] = *(const short8*)(pA + mf * 2048 + ks * 1024);
#pragma unroll
        for (int nf = 0; nf < 2; ++nf)
#pragma unroll
            for (int ks = 0; ks < 2; ++ks)
                B0[nf][ks] = *(const short8*)(pB + nf * 2048 + ks * 1024);
        stageP(A, Bt, bmbase, bn, 4 * T + 6, smem, r0, c0, wq);
        MIDBAR();
        PHASE_MFMA(A0, B0, 0, 0);
        ENDBAR();

        // phase 1
#pragma unroll
        for (int mf = 0; mf < 4; ++mf)
#pragma unroll
            for (int ks = 0; ks < 2; ++ks)
                A1[mf][ks] = *(const short8*)(pA + (4 + mf) * 2048 + ks * 1024);
#pragma unroll
        for (int nf = 0; nf < 2; ++nf)
#pragma unroll
            for (int ks = 0; ks < 2; ++ks)
                B1[nf][ks] = *(const short8*)(pB + (2 + nf) * 2048 + ks * 1024);
        stageP(A, Bt, bmbase, bn, 4 * T + 7, smem, r0, c0, wq);
        MIDBAR();
        PHASE_MFMA(A1, B0, 4, 0);
        ENDBAR();

        // phase 2
        stageP(A, Bt, bmbase, bn, 4 * T + 8, smem, r0, c0, wq);
        MIDBAR();
        PHASE_MFMA(A1, B1, 4, 2);
        ENDBAR();

        // phase 3
        stageP(A, Bt, bmbase, bn, 4 * T + 9, smem, r0, c0, wq);
        if (T < NT_TOT - 2)       { asm volatile("s_waitcnt vmcnt(4)" ::: "memory"); }
        else if (T == NT_TOT - 2) { asm volatile("s_waitcnt vmcnt(0)" ::: "memory"); }
        MIDBAR();
        PHASE_MFMA(A0, B1, 0, 2);
        ENDBAR();

        // per-output-tile epilogue: LDS-transpose (separate scratch region, no collision with
        // in-flight gl_lds of tiles T+1/T+2) + NT coalesced stores.
        if ((T & 7) == 7) {
            int bm = bmbase + (T >> 3);
            float* ep = (float*)(smem + EP_OFF) + w * (16 * 40);
            const float* bls = (const float*)(smem + BIAS_OFF);
            int rl = l >> 4, slot = l & 15;
            int rbase = (bm << 8) + (wm << 7);
            int cbase = (bn << 8) + (wn << 6);
            float bs[4];
#pragma unroll
            for (int nf = 0; nf < 4; ++nf) bs[nf] = bls[(wn << 6) + nf * 16 + slot];
#pragma unroll
            for (int mf = 0; mf < 8; ++mf) {
#pragma unroll
                for (int nfp = 0; nfp < 2; ++nfp) {
#pragma unroll
                    for (int nf2 = 0; nf2 < 2; ++nf2)
#pragma unroll
                        for (int j = 0; j < 4; ++j)
                            ep[(rl * 4 + j) * 40 + nf2 * 16 + slot] =
                                acc[mf][nfp * 2 + nf2][j] + bs[nfp * 2 + nf2];
                    asm volatile("s_waitcnt lgkmcnt(0)" ::: "memory");
#pragma unroll
                    for (int p = 0; p < 2; ++p) {
                        int r = p * 8 + (l >> 3);
                        f32x4 vv = *(const f32x4*)(ep + r * 40 + (l & 7) * 4);
                        __builtin_nontemporal_store(vv,
                            (f32x4*)(C + (size_t)(rbase + mf * 16 + r) * VOCAB_ +
                                     cbase + nfp * 32 + (l & 7) * 4));
                    }
                    asm volatile("s_waitcnt lgkmcnt(0)" ::: "memory");
                }
#pragma unroll
                for (int nf = 0; nf < 4; ++nf) acc[mf][nf] = f32x4{0.f, 0.f, 0.f, 0.f};
            }
        }
    }
}

// ---------------- minGRU scan ----------------
__device__ __forceinline__ void gate_terms(float k, float hp, float& a, float& b) {
    float z = 1.f / (1.f + __expf(-k));
    a = 1.f - z;
    float g = (hp >= 0.f) ? (hp + 0.5f) : (1.f / (1.f + __expf(-hp)));
    b = z * g;
}

__global__ __launch_bounds__(256) void scan1_k(
    const float* __restrict__ proj, float* __restrict__ Ach, float* __restrict__ Bch) {
    int t = blockIdx.x * 256 + threadIdx.x;
    int h = t & (HID_ - 1);
    int bc = t >> 9;
    int b = bc >> 5, c = bc & (NCHUNK - 1);
    const float* p = proj + ((size_t)(b * S_ + c * CHUNK)) * (2 * HID_) + h;
    float A = 1.f, H = 0.f;
#pragma unroll 4
    for (int s = 0; s < CHUNK; s++) {
        float k = p[(size_t)s * (2 * HID_)];
        float hp = p[(size_t)s * (2 * HID_) + HID_];
        float a, bb;
        gate_terms(k, hp, a, bb);
        H = a * H + bb;
        A *= a;
    }
    Ach[t] = A;
    Bch[t] = H;
}

__global__ __launch_bounds__(256) void scan23_k(
    const float* __restrict__ proj, const float* __restrict__ Ach,
    const float* __restrict__ Bch, float* __restrict__ xres) {
    int t = blockIdx.x * 256 + threadIdx.x;
    int h = t & (HID_ - 1);
    int bc = t >> 9;
    int b = bc >> 5, c = bc & (NCHUNK - 1);
    float H = 0.f;
    for (int cp = 0; cp < c; cp++) {
        int idx = (b * NCHUNK + cp) * HID_ + h;
        H = Ach[idx] * H + Bch[idx];
    }
    const float* p = proj + ((size_t)(b * S_ + c * CHUNK)) * (2 * HID_) + h;
    float* x = xres + ((size_t)(b * S_ + c * CHUNK)) * HID_ + h;
#pragma unroll 4
    for (int s = 0; s < CHUNK; s++) {
        float k = p[(size_t)s * (2 * HID_)];
        float hp = p[(size_t)s * (2 * HID_) + HID_];
        float a, bb;
        gate_terms(k, hp, a, bb);
        H = a * H + bb;
        x[(size_t)s * HID_] += H;
    }
}

// ---------------- launch ----------------
extern "C" void kernel_launch(void* const* d_in, const int* in_sizes, int n_in,
                              void* d_out, int out_size, void* d_ws, size_t ws_size,
                              hipStream_t stream) {
    const int* ids = (const int*)d_in[0];
    const float* emb = (const float*)d_in[1];
    const float* W0 = (const float*)d_in[2];
    const float* W1 = (const float*)d_in[3];
    const float* ln0_g = (const float*)d_in[4];
    const float* ln0_b = (const float*)d_in[5];
    const float* ln1_g = (const float*)d_in[6];
    const float* ln1_b = (const float*)d_in[7];
    const float* lnf_g = (const float*)d_in[8];
    const float* lnf_b = (const float*)d_in[9];
    const float* fc_w = (const float*)d_in[10];
    const float* fc_b = (const float*)d_in[11];
    float* out = (float*)d_out;

    (void)hipFuncSetAttribute((const void*)gemmP_k,
                              hipFuncAttributeMaxDynamicSharedMemorySize, SMEM_TOT);

    char* ws = (char*)d_ws;
    const size_t OFF_XW   = 0;
    const size_t OFF_PROJ = 8388608;
    const size_t OFF_XRES = OFF_PROJ + 33554432;
    const size_t OFF_WT0  = OFF_XRES + 16777216;
    const size_t OFF_WT1  = OFF_WT0 + 1048576;
    const size_t OFF_SA   = OFF_WT1 + 1048576;
    const size_t OFF_SB   = OFF_SA + 262144;
    const size_t OFF_FCWT = OFF_SB + 262144;
    const size_t NEED_BIG = OFF_FCWT + 32768000;

    unsigned short* xw  = (unsigned short*)(ws + OFF_XW);
    float* proj         = (float*)(ws + OFF_PROJ);
    float* xres         = (float*)(ws + OFF_XRES);
    unsigned short* wt0 = (unsigned short*)(ws + OFF_WT0);
    unsigned short* wt1 = (unsigned short*)(ws + OFF_WT1);
    float* sA = (float*)(ws + OFF_SA);
    float* sB = (float*)(ws + OFF_SB);

    bool big = ws_size >= NEED_BIG;
    unsigned short* fcwt = big ? (unsigned short*)(ws + OFF_FCWT)
                               : (unsigned short*)(ws + OFF_PROJ);

    if (big) {
        prep_k<<<2048 + 1024 + 16000, 256, 0, stream>>>(
            ids, emb, ln0_g, ln0_b, xres, xw, W0, wt0, W1, wt1, fc_w, fcwt);
    } else {
        prep_k<<<2048 + 1024, 256, 0, stream>>>(
            ids, emb, ln0_g, ln0_b, xres, xw, W0, wt0, W1, wt1, fc_w, wt0);
    }

    // layer 0
    gemm_bf16_k<<<dim3(1024 / 128, ROWS / 128), 256, 0, stream>>>(xw, wt0, proj, ROWS, 1024, 512);
    scan1_k<<<65536 / 256, 256, 0, stream>>>(proj, sA, sB);
    scan23_k<<<65536 / 256, 256, 0, stream>>>(proj, sA, sB, xres);

    // layer 1
    ln_k<<<ROWS / 4, 256, 0, stream>>>(xres, ln1_g, ln1_b, xw, 1e-5f);
    gemm_bf16_k<<<dim3(1024 / 128, ROWS / 128), 256, 0, stream>>>(xw, wt1, proj, ROWS, 1024, 512);
    scan1_k<<<65536 / 256, 256, 0, stream>>>(proj, sA, sB);
    scan23_k<<<65536 / 256, 256, 0, stream>>>(proj, sA, sB, xres);

    // final LN (eps=0.0) + logits (persistent col-major 8-phase GEMM)
    ln_k<<<ROWS / 4, 256, 0, stream>>>(xres, lnf_g, lnf_b, xw, 0.0f);
    if (!big) {
        transpose_convert_k<<<dim3(VOCAB_ / 32, 512 / 32), 256, 0, stream>>>(fc_w, fcwt, 512, VOCAB_);
    }
    gemmP_k<<<NBLK_F, 512, SMEM_TOT, stream>>>(xw, fcwt, fc_b, out);
}